// Round 4
// baseline (500.649 us; speedup 1.0000x reference)
//
#include <hip/hip_runtime.h>
#include <hip/hip_bf16.h>
#include <stdint.h>

#define NB 32
#define NS 4096
#define ND 512

typedef __attribute__((ext_vector_type(8))) short short8;
typedef __attribute__((ext_vector_type(4))) float floatx4;

__device__ __forceinline__ short f2bf(float f) {
    unsigned int u = __builtin_bit_cast(unsigned int, f);
    return (short)((u + 0x8000u) >> 16);
}

__device__ __forceinline__ float fast_tanh(float x) {
    float e = __expf(2.0f * x);
    return 1.0f - 2.0f * __builtin_amdgcn_rcpf(e + 1.0f);
}

__device__ __forceinline__ short8 pack8(float4 a, float4 b) {
    short8 w;
    w[0] = f2bf(a.x); w[1] = f2bf(a.y); w[2] = f2bf(a.z); w[3] = f2bf(a.w);
    w[4] = f2bf(b.x); w[5] = f2bf(b.y); w[6] = f2bf(b.z); w[7] = f2bf(b.w);
    return w;
}

// ---------- K1a: qb[b][e] = query[b] . W1[:,e] + b1[e] + b2[e] ----------
__global__ void __launch_bounds__(256) qproj_kernel(
    const float* __restrict__ query, const float* __restrict__ W1,
    const float* __restrict__ b1, const float* __restrict__ b2,
    float* __restrict__ qb) {
    const int b  = blockIdx.x;
    const int es = blockIdx.y;
    const int t  = threadIdx.x;
    const int col = t & 63, kc = t >> 6;
    __shared__ float q[ND];
    __shared__ float red[256];
    q[t] = query[b * ND + t];
    q[t + 256] = query[b * ND + t + 256];
    __syncthreads();
    float acc = 0.f;
    const float* wp = W1 + (size_t)(kc * 128) * ND + es * 64 + col;
    const float* qp = q + kc * 128;
#pragma unroll 8
    for (int k = 0; k < 128; k++)
        acc += qp[k] * wp[(size_t)k * ND];
    red[t] = acc;
    __syncthreads();
    if (t < 64) {
        float s = red[t] + red[t + 64] + red[t + 128] + red[t + 192];
        int e = es * 64 + t;
        qb[b * ND + e] = s + b1[e] + b2[e];
    }
}

// ---------- K1b: W2 (fp32 [k][e]) -> bf16 tiled W2Tt ----------
// chunk g = (nt:1 | ks:4 | kq:2 | n:8); holds bf16(W2[ks*32+kq*8+j][nt*256+n]), j=0..7
__global__ void __launch_bounds__(256) w2t_kernel(
    const float* __restrict__ W2, unsigned short* __restrict__ W2Tt) {
    int g = blockIdx.x * 256 + threadIdx.x;   // 32768 chunks
    int nt = g >> 14;
    int ks = (g >> 10) & 15;
    int kq = (g >> 8) & 3;
    int n  = g & 255;
    int e  = nt * 256 + n;
    int k0 = ks * 32 + kq * 8;
    short8 v;
#pragma unroll
    for (int j = 0; j < 8; j++)
        v[j] = f2bf(W2[(size_t)(k0 + j) * ND + e]);
    *(short8*)&W2Tt[(size_t)g * 8] = v;
}

// ---------- K1c: values fp32 -> bf16 k-step-tiled vbfT ----------
// vbfT[(b*16+ks)*4096 + s]*32 + kq*8  holds bf16(values[b][s][ks*32+kq*8+j]) j=0..7
__global__ void __launch_bounds__(256) vconv_kernel(
    const float* __restrict__ values, unsigned short* __restrict__ vbfT) {
    size_t g = (size_t)blockIdx.x * 256 + threadIdx.x;   // 8,388,608 chunks
    int kk = (int)(g & 63);          // ks*4 + kq
    size_t bs = g >> 6;              // b*4096 + s
    int b = (int)(bs >> 12), s = (int)(bs & 4095);
    const float4* src = (const float4*)(values + g * 8);
    float4 x0 = src[0], x1 = src[1];
    short8 w = pack8(x0, x1);
    int ks = kk >> 2, kq = kk & 3;
    *(short8*)&vbfT[((size_t)(b * 16 + ks) * 4096 + s) * 32 + kq * 8] = w;
}

// ---------- staging helper: 6 global_load_lds ops (B:4, A:2), 24 KB ----------
__device__ __forceinline__ void stage_step(
    const unsigned short* bsrc, const unsigned short* asrc,
    unsigned short* sB, unsigned short* sA, int tid) {
#pragma unroll
    for (int r = 0; r < 4; r++) {
        int c = tid + 256 * r;
        __builtin_amdgcn_global_load_lds(
            (const __attribute__((address_space(1))) unsigned int*)(bsrc + c * 8),
            (__attribute__((address_space(3))) unsigned int*)(sB + c * 8), 16, 0, 0);
    }
#pragma unroll
    for (int r = 0; r < 2; r++) {
        int c = tid + 256 * r;
        __builtin_amdgcn_global_load_lds(
            (const __attribute__((address_space(1))) unsigned int*)(asrc + c * 8),
            (__attribute__((address_space(3))) unsigned int*)(sA + c * 8), 16, 0, 0);
    }
}

// ---------- K2: scores += sum_n tanh((values@W2)[s][n] + qb[n]) * V[n] ----------
// Tile 128 s x 256 n, K=512 in 16 steps of 32. 4 waves, each 64x128 (acc 4x8).
// 3 LDS buffers, prefetch distance 2, manual s_waitcnt vmcnt(6) + raw s_barrier:
// in-flight prefetches survive the barrier (the m97 barrier-drain fix).
__global__ void __launch_bounds__(256, 2) scores_kernel(
    const unsigned short* __restrict__ vbfT, const unsigned short* __restrict__ W2Tt,
    const float* __restrict__ qb, const float* __restrict__ V,
    float* __restrict__ scores) {
    const int nt = blockIdx.x;   // 0..1
    const int st = blockIdx.y;   // 0..31
    const int b  = blockIdx.z;   // 0..31
    const int n0 = nt * 256, s0 = st * 128;

    __shared__ __align__(16) unsigned short sA[3][4096];   // 3 x 8 KB: 128 rows x 32 k
    __shared__ __align__(16) unsigned short sB[3][8192];   // 3 x 16 KB: kq-major, 256 n x 32 k
    __shared__ float sQb[256];
    __shared__ float sV[256];

    const int tid  = threadIdx.x;
    const int lane = tid & 63;
    const int wave = tid >> 6;
    const int wr = wave >> 1, wc = wave & 1;
    const int mr = lane & 15;
    const int q  = lane >> 4;

    sQb[tid] = qb[b * ND + n0 + tid];
    sV[tid]  = V[n0 + tid];
    __syncthreads();

    const unsigned short* aplane = vbfT + (size_t)b * 16 * 131072 + (size_t)s0 * 32; // + ks*131072 + c*8
    const unsigned short* bbase  = W2Tt + (size_t)nt * 131072;                       // + ks*8192  + c*8

    floatx4 acc[4][8] = {};

    // prologue: prefetch steps 0 and 1
    stage_step(bbase, aplane, &sB[0][0], &sA[0][0], tid);
    stage_step(bbase + 8192, aplane + 131072, &sB[1][0], &sA[1][0], tid);

    const int aoff = (wr * 64 + mr) * 32 + q * 8;        // + i*512
    const int boff = (q * 256 + wc * 128 + mr) * 8;      // + j*128

#pragma unroll
    for (int ks = 0; ks < 16; ks++) {
        // wait only the oldest 6 loads (= this step's); keep next step's in flight
        if (ks == 15) __builtin_amdgcn_s_waitcnt(0x0F70);  // vmcnt(0), lgkm/exp don't-care
        else          __builtin_amdgcn_s_waitcnt(0x0F76);  // vmcnt(6)
        __builtin_amdgcn_s_barrier();
        __builtin_amdgcn_sched_barrier(0);   // pin: no ds_read hoists above the barrier

        const int cur = ks % 3;
        short8 af[4], bfr[8];
#pragma unroll
        for (int i = 0; i < 4; i++)
            af[i] = *(const short8*)&sA[cur][aoff + i * 512];
#pragma unroll
        for (int j = 0; j < 8; j++)
            bfr[j] = *(const short8*)&sB[cur][boff + j * 128];

        if (ks < 14) {
            stage_step(bbase + (size_t)(ks + 2) * 8192,
                       aplane + (size_t)(ks + 2) * 131072,
                       &sB[(ks + 2) % 3][0], &sA[(ks + 2) % 3][0], tid);
        }

#pragma unroll
        for (int i = 0; i < 4; i++)
#pragma unroll
            for (int j = 0; j < 8; j++)
                acc[i][j] = __builtin_amdgcn_mfma_f32_16x16x32_bf16(af[i], bfr[j], acc[i][j], 0, 0, 0);
    }

    // epilogue: tanh(P + qb) * V, reduce over n, atomic partial per s-row
    float vcoef[8], qadd[8];
#pragma unroll
    for (int j = 0; j < 8; j++) {
        int col = wc * 128 + j * 16 + mr;
        vcoef[j] = sV[col];
        qadd[j]  = sQb[col];
    }
#pragma unroll
    for (int i = 0; i < 4; i++) {
#pragma unroll
        for (int r = 0; r < 4; r++) {
            float p = 0.f;
#pragma unroll
            for (int j = 0; j < 8; j++)
                p += fast_tanh(acc[i][j][r] + qadd[j]) * vcoef[j];
            p += __shfl_xor(p, 1);
            p += __shfl_xor(p, 2);
            p += __shfl_xor(p, 4);
            p += __shfl_xor(p, 8);
            if (mr == 0) {
                int row = wr * 64 + i * 16 + q * 4 + r;
                atomicAdd(&scores[(size_t)b * NS + s0 + row], p);
            }
        }
    }
}

// ---------- K3: softmax over S per batch ----------
__global__ void __launch_bounds__(256) softmax_kernel(
    const float* __restrict__ scores, float* __restrict__ attn) {
    int b = blockIdx.x;
    int t = threadIdx.x;
    __shared__ float red[4];
    __shared__ float bcast[2];
    const float* sc = scores + (size_t)b * NS;
    float v[16];
    float m = -1e30f;
#pragma unroll
    for (int i = 0; i < 16; i++) { v[i] = sc[t + i * 256]; m = fmaxf(m, v[i]); }
    for (int o = 32; o; o >>= 1) m = fmaxf(m, __shfl_xor(m, o));
    if ((t & 63) == 0) red[t >> 6] = m;
    __syncthreads();
    if (t == 0) bcast[0] = fmaxf(fmaxf(red[0], red[1]), fmaxf(red[2], red[3]));
    __syncthreads();
    m = bcast[0];
    float sum = 0.f;
#pragma unroll
    for (int i = 0; i < 16; i++) { v[i] = __expf(v[i] - m); sum += v[i]; }
    for (int o = 32; o; o >>= 1) sum += __shfl_xor(sum, o);
    if ((t & 63) == 0) red[t >> 6] = sum;
    __syncthreads();
    if (t == 0) bcast[1] = red[0] + red[1] + red[2] + red[3];
    __syncthreads();
    float inv = 1.0f / bcast[1];
    float* ao = attn + (size_t)b * NS;
#pragma unroll
    for (int i = 0; i < 16; i++) ao[t + i * 256] = v[i] * inv;
}

// ---------- K4a: pctx[sc][b][d] = sum_{s in 512-chunk} attn * values (bf16 from vbfT) ----------
__global__ void __launch_bounds__(256) context_partial_kernel(
    const unsigned short* __restrict__ vbfT, const float* __restrict__ attn,
    float* __restrict__ pctx) {
    const int ks = blockIdx.x;  // 0..15 (owns d = ks*32 .. +31 exclusively)
    const int sc = blockIdx.y;  // 0..7
    const int b  = blockIdx.z;  // 0..31
    const int t  = threadIdx.x;
    __shared__ float sAttn[512];
    __shared__ float redx[256], redy[256];
    sAttn[t]       = attn[(size_t)b * NS + sc * 512 + t];
    sAttn[t + 256] = attn[(size_t)b * NS + sc * 512 + t + 256];
    __syncthreads();
    const int dpair = t & 15, spar = t >> 4;
    const unsigned short* plane = vbfT + ((size_t)(b * 16 + ks) * 4096 + sc * 512) * 32;
    float ax = 0.f, ay = 0.f;
#pragma unroll 4
    for (int i = 0; i < 32; i++) {
        int s = spar + 16 * i;
        unsigned int u = *(const unsigned int*)&plane[(size_t)s * 32 + dpair * 2];
        float vx = __builtin_bit_cast(float, u << 16);
        float vy = __builtin_bit_cast(float, u & 0xFFFF0000u);
        float a = sAttn[s];
        ax += a * vx; ay += a * vy;
    }
    redx[t] = ax; redy[t] = ay;
    __syncthreads();
    if (t < 16) {
        float sx = 0.f, sy = 0.f;
#pragma unroll
        for (int sp = 0; sp < 16; sp++) { sx += redx[sp * 16 + t]; sy += redy[sp * 16 + t]; }
        int d = ks * 32 + t * 2;
        pctx[((size_t)sc * 32 + b) * ND + d]     = sx;
        pctx[((size_t)sc * 32 + b) * ND + d + 1] = sy;
    }
}

// ---------- K4b: ctx[b][d] = sum_sc pctx[sc][b][d] ----------
__global__ void __launch_bounds__(256) context_reduce_kernel(
    const float* __restrict__ pctx, float* __restrict__ ctx) {
    int i = blockIdx.x * 256 + threadIdx.x;  // 16384
    float s = 0.f;
#pragma unroll
    for (int p = 0; p < 8; p++) s += pctx[(size_t)p * (32 * ND) + i];
    ctx[i] = s;
}

extern "C" void kernel_launch(void* const* d_in, const int* in_sizes, int n_in,
                              void* d_out, int out_size, void* d_ws, size_t ws_size,
                              hipStream_t stream) {
    const float* query  = (const float*)d_in[0];
    const float* values = (const float*)d_in[1];
    const float* W1     = (const float*)d_in[2];
    const float* b1     = (const float*)d_in[3];
    const float* W2     = (const float*)d_in[4];
    const float* b2     = (const float*)d_in[5];
    const float* V      = (const float*)d_in[6];
    // d_in[7] = bv: uniform shift over softmax axis -> no effect on outputs. Dropped.

    float* ctx_out  = (float*)d_out;               // [32,512]
    float* attn_out = (float*)d_out + NB * ND;     // [32,4096]

    char* ws = (char*)d_ws;
    unsigned short* vbfT   = (unsigned short*)ws;                          // 128 MB
    const size_t VB = (size_t)NB * NS * ND * 2;
    float*          qb     = (float*)(ws + VB);                            // 64 KB
    unsigned short* W2Tt   = (unsigned short*)(ws + VB + (64 << 10));      // 512 KB
    float*          scores = (float*)(ws + VB + (576 << 10));              // 512 KB
    float*          pctx   = (float*)(ws + VB + (1088 << 10));             // 512 KB

    hipMemsetAsync(scores, 0, (size_t)NB * NS * sizeof(float), stream);

    vconv_kernel<<<32768, 256, 0, stream>>>(values, vbfT);
    w2t_kernel<<<128, 256, 0, stream>>>(W2, W2Tt);
    qproj_kernel<<<dim3(NB, 8), 256, 0, stream>>>(query, W1, b1, b2, qb);
    scores_kernel<<<dim3(2, 32, 32), 256, 0, stream>>>(vbfT, W2Tt, qb, V, scores);
    softmax_kernel<<<NB, 256, 0, stream>>>(scores, attn_out);
    context_partial_kernel<<<dim3(16, 8, 32), 256, 0, stream>>>(vbfT, attn_out, pctx);
    context_reduce_kernel<<<64, 256, 0, stream>>>(pctx, ctx_out);
}